// Round 1
// baseline (15.956 us; speedup 1.0000x reference)
//
#include <hip/hip_runtime.h>

// StateStack forward on MI355X.
//
// Reference semantics:
//   new_stack = hidden_stack.at[pos+1, b].set(x)
//   out[k,b,:] = new_stack[pos[b]-1+k, b, :]   k in {0,1}
// Since pos+1 != pos-1 and pos+1 != pos (pos in [1,64]), the scatter is
// invisible to the gather -> output reads hidden_stack directly. x / op dead.
//
// Layout (row-major): hidden_stack[(s*BATCH + b)*HIDDEN + h], s in [0,66).
// Pure memory-bound gather: 32 MB read (2KB contiguous aligned chunks per
// batch-row) + 32 MB linear write.

#define SEQ_LEN 64
#define BATCH   8192
#define HIDDEN  512
#define H4      (HIDDEN / 4)   // 128 float4 per row

__global__ __launch_bounds__(256) void StateStack_gather_kernel(
    const float4* __restrict__ stack,   // (SEQ_LEN+2, BATCH, H4) as float4
    const int*    __restrict__ pos,     // (BATCH,)
    float4*       __restrict__ out)     // (2, BATCH, H4) as float4
{
    int tid = blockIdx.x * blockDim.x + threadIdx.x;   // 0 .. 2*BATCH*H4
    int h4 = tid & (H4 - 1);
    int bk = tid >> 7;                 // = b + k*BATCH
    int b  = bk & (BATCH - 1);
    int k  = bk >> 13;                 // 0 or 1
    int row = pos[b] - 1 + k;          // in [0, 64]
    size_t src = ((size_t)row * BATCH + (size_t)b) * H4 + h4;
    out[tid] = stack[src];
}

extern "C" void kernel_launch(void* const* d_in, const int* in_sizes, int n_in,
                              void* d_out, int out_size, void* d_ws, size_t ws_size,
                              hipStream_t stream) {
    // inputs (setup_inputs dict order): x, hidden_stack, op, pos
    const float4* stack = (const float4*)d_in[1];
    const int*    pos   = (const int*)d_in[3];
    float4*       out   = (float4*)d_out;

    const int total4 = 2 * BATCH * H4;          // 2,097,152 float4
    const int block  = 256;
    const int grid   = total4 / block;          // 8192 blocks
    StateStack_gather_kernel<<<grid, block, 0, stream>>>(stack, pos, out);
}